// Round 1
// baseline (13645.567 us; speedup 1.0000x reference)
//
#include <hip/hip_runtime.h>
#include <stdint.h>

// Problem dims (fixed)
#define B_  256
#define T_  1024
#define D_  128
#define H_  512
#define G4_ 2048            // 4*H
#define BT_ (B_ * T_)

typedef unsigned short u16;
typedef __attribute__((ext_vector_type(8))) short  bf16x8;  // 8 bf16 in 4 VGPRs
typedef __attribute__((ext_vector_type(8))) u16    u16x8;
typedef __attribute__((ext_vector_type(4))) float  f32x4;

static __device__ __forceinline__ u16 f2bf(float f) {
  uint32_t u = __builtin_bit_cast(uint32_t, f);
  u += 0x7FFFu + ((u >> 16) & 1u);   // RNE
  return (u16)(u >> 16);
}

static __device__ __forceinline__ u16x8 pack8(float4 a, float4 b) {
  u16x8 p;
  p[0] = f2bf(a.x); p[1] = f2bf(a.y); p[2] = f2bf(a.z); p[3] = f2bf(a.w);
  p[4] = f2bf(b.x); p[5] = f2bf(b.y); p[6] = f2bf(b.z); p[7] = f2bf(b.w);
  return p;
}

static __device__ __forceinline__ float fast_sig(float x) {
  return 1.f / (1.f + __expf(-x));
}
static __device__ __forceinline__ float fast_tanh(float x) {
  // 1 - 2/(e^{2x}+1); correct limits at +-inf
  return 1.f - 2.f / (__expf(2.f * x) + 1.f);
}

// ---------------------------------------------------------------------------
// prep: bf16 weight copies, bias sum, zero c-state and out[:,0,:]
// ---------------------------------------------------------------------------
__global__ void prep_kernel(const float* __restrict__ Whh, const float* __restrict__ Wih,
                            const float* __restrict__ w1,  const float* __restrict__ w2,
                            const float* __restrict__ b_ih, const float* __restrict__ b_hh,
                            u16* __restrict__ Whh_bf, u16* __restrict__ Wih_bf,
                            u16* __restrict__ w1y_bf, u16* __restrict__ w2_bf,
                            float* __restrict__ w1s, float* __restrict__ bsum,
                            float* __restrict__ cst, float* __restrict__ Yd) {
  const int idx = blockIdx.x * blockDim.x + threadIdx.x;
  if (idx < G4_ * H_) Whh_bf[idx] = f2bf(Whh[idx]);          // 1,048,576
  if (idx < G4_ * D_) Wih_bf[idx] = f2bf(Wih[idx]);          // 262,144
  if (idx < H_ * H_) {                                       // 262,144
    const int n = idx >> 9, k = idx & 511;
    w1y_bf[idx] = f2bf(w1[n * 513 + 1 + k]);                 // w1[:,1:]
    w2_bf[idx]  = f2bf(w2[idx]);
  }
  if (idx < H_)  w1s[idx]  = w1[idx * 513];                  // w1[:,0]
  if (idx < G4_) bsum[idx] = b_ih[idx] + b_hh[idx];
  if (idx < B_ * H_) {                                       // 131,072
    cst[idx] = 0.f;
    const int b = idx >> 9, h = idx & 511;
    Yd[(size_t)b * T_ * H_ + h] = 0.f;                       // out[b,0,:] = h_0 = 0
  }
}

// ---------------------------------------------------------------------------
// Phase 1: one LSTM step. Reads h_i from d_out rows (b, step), writes h_{i+1}
// to d_out rows (b, step+1) and updates c in ws. MFMA bf16, K = 512(h)+128(x).
// Block: 256 thr = 4 waves; tile = 32 batch x 32 hcols; wave w owns gate w.
// Grid: (16 hcol-tiles, 8 batch-tiles).
// ---------------------------------------------------------------------------
__launch_bounds__(256)
__global__ void lstm_step_kernel(const float* __restrict__ x,
                                 const u16* __restrict__ Whh_bf,
                                 const u16* __restrict__ Wih_bf,
                                 const float* __restrict__ bsum,
                                 float* __restrict__ cst,
                                 float* __restrict__ Yd,
                                 int step) {
  __shared__ u16   As[32][136];        // 32 x 128 K-chunk, pad->stride 272B (bank-safe)
  __shared__ float Gs[4][32][33];      // gate exchange

  const int tid  = threadIdx.x;
  const int lane = tid & 63;
  const int w    = tid >> 6;           // gate index 0..3 (i,f,g,o)
  const int hc0  = blockIdx.x * 32;
  const int br0  = blockIdx.y * 32;

  f32x4 acc[2][2] = {};

  const int srow = tid >> 3;           // 0..31
  const int scol = (tid & 7) * 16;     // 0..112

  for (int kc = 0; kc < 5; ++kc) {     // 5 chunks of K=128 (4x h, 1x x)
    // --- stage A chunk (convert fp32 -> bf16) ---
    const float* src;
    if (kc < 4) {
      src = &Yd[((size_t)(br0 + srow) * T_ + step) * H_ + kc * 128 + scol];
    } else {
      src = &x[((size_t)(br0 + srow) * T_ + step) * D_ + scol];
    }
    {
      const float4* s4 = (const float4*)src;
      float4 f0 = s4[0], f1 = s4[1], g0 = s4[2], g1 = s4[3];
      *(u16x8*)&As[srow][scol]     = pack8(f0, f1);
      *(u16x8*)&As[srow][scol + 8] = pack8(g0, g1);
    }
    __syncthreads();

    // --- MFMA over chunk: 4 k-steps of 32 ---
    for (int ks = 0; ks < 4; ++ks) {
      const int klocal = ks * 32 + ((lane >> 4) << 3);
      bf16x8 a0 = *(const bf16x8*)&As[lane & 15][klocal];
      bf16x8 a1 = *(const bf16x8*)&As[16 + (lane & 15)][klocal];
      const int j0 = w * 512 + hc0 + (lane & 15);
      bf16x8 b0, b1;
      if (kc < 4) {
        const int kglob = kc * 128 + klocal;
        b0 = *(const bf16x8*)(Whh_bf + (size_t)j0 * H_ + kglob);
        b1 = *(const bf16x8*)(Whh_bf + (size_t)(j0 + 16) * H_ + kglob);
      } else {
        b0 = *(const bf16x8*)(Wih_bf + (size_t)j0 * D_ + klocal);
        b1 = *(const bf16x8*)(Wih_bf + (size_t)(j0 + 16) * D_ + klocal);
      }
      acc[0][0] = __builtin_amdgcn_mfma_f32_16x16x32_bf16(a0, b0, acc[0][0], 0, 0, 0);
      acc[0][1] = __builtin_amdgcn_mfma_f32_16x16x32_bf16(a0, b1, acc[0][1], 0, 0, 0);
      acc[1][0] = __builtin_amdgcn_mfma_f32_16x16x32_bf16(a1, b0, acc[1][0], 0, 0, 0);
      acc[1][1] = __builtin_amdgcn_mfma_f32_16x16x32_bf16(a1, b1, acc[1][1], 0, 0, 0);
    }
    __syncthreads();
  }

  // --- exchange gates via LDS ---
  for (int mt = 0; mt < 2; ++mt)
    for (int nt = 0; nt < 2; ++nt)
      for (int r = 0; r < 4; ++r)
        Gs[w][mt * 16 + ((lane >> 4) << 2) + r][nt * 16 + (lane & 15)] = acc[mt][nt][r];
  __syncthreads();

  // --- elementwise LSTM update: thread -> (bl, 4 cols) ---
  const int bl = tid >> 3;
  const int c0 = (tid & 7) * 4;
  const int br = br0 + bl;
  for (int u = 0; u < 4; ++u) {
    const int col = c0 + u;
    const int jb  = hc0 + col;
    const float gi = Gs[0][bl][col] + bsum[jb];
    const float gf = Gs[1][bl][col] + bsum[512 + jb];
    const float gg = Gs[2][bl][col] + bsum[1024 + jb];
    const float go = Gs[3][bl][col] + bsum[1536 + jb];
    const size_t cidx = (size_t)br * H_ + jb;
    const float cn = fast_sig(gf) * cst[cidx] + fast_sig(gi) * fast_tanh(gg);
    cst[cidx] = cn;
    Yd[((size_t)br * T_ + (step + 1)) * H_ + jb] = fast_sig(go) * fast_tanh(cn);
  }
}

// ---------------------------------------------------------------------------
// Phase 2: GEMM (M=BT, N=512, K=512), 128x128 tile, BK=64, 4 waves (2x2).
// MODE 0: A = Y fp32 (d_out, converted on stage); epi: Abf = bf16(tanh(acc + b1 + s*w1s))
// MODE 1: A = Abf bf16;                           epi: Yd += dt * t[row] * (acc + b2)
// ---------------------------------------------------------------------------
template <int MODE>
__launch_bounds__(256)
__global__ void ode_gemm(const void* __restrict__ Asrc,
                         const u16* __restrict__ Wbf,
                         const float* __restrict__ bias,
                         const float* __restrict__ aux,   // MODE0: w1s ; MODE1: t (BT)
                         float* __restrict__ Yd,
                         u16* __restrict__ Abf_out,
                         float sval) {                    // MODE0: s ; MODE1: dt
  __shared__ u16 As[128][72];
  __shared__ u16 Bs[128][72];

  const int tid  = threadIdx.x;
  const int lane = tid & 63;
  const int wid  = tid >> 6;
  const int wm   = wid >> 1, wn = wid & 1;
  const int n0   = blockIdx.x * 128;
  const size_t m0 = (size_t)blockIdx.y * 128;

  f32x4 acc[4][4] = {};

  const int srow = tid >> 1;           // 0..127
  const int sc0  = (tid & 1) * 32;     // 0 / 32

  for (int kc = 0; kc < 8; ++kc) {
    const int k0 = kc * 64;
    // stage A
    if (MODE == 0) {
      const float4* s4 = (const float4*)((const float*)Asrc + (m0 + srow) * 512 + k0 + sc0);
      for (int u = 0; u < 4; ++u) {
        float4 fa = s4[2 * u], fb = s4[2 * u + 1];
        *(u16x8*)&As[srow][sc0 + u * 8] = pack8(fa, fb);
      }
    } else {
      const u16* s = (const u16*)Asrc + (m0 + srow) * 512 + k0 + sc0;
      for (int u = 0; u < 4; ++u)
        *(u16x8*)&As[srow][sc0 + u * 8] = *(const u16x8*)(s + u * 8);
    }
    // stage B (bf16 weights, row-major [N][K])
    {
      const u16* s = Wbf + (size_t)(n0 + srow) * 512 + k0 + sc0;
      for (int u = 0; u < 4; ++u)
        *(u16x8*)&Bs[srow][sc0 + u * 8] = *(const u16x8*)(s + u * 8);
    }
    __syncthreads();

    for (int ks = 0; ks < 2; ++ks) {
      const int kl = ks * 32 + ((lane >> 4) << 3);
      bf16x8 af[4], bfv[4];
      for (int mt = 0; mt < 4; ++mt)
        af[mt] = *(const bf16x8*)&As[wm * 64 + mt * 16 + (lane & 15)][kl];
      for (int nt = 0; nt < 4; ++nt)
        bfv[nt] = *(const bf16x8*)&Bs[wn * 64 + nt * 16 + (lane & 15)][kl];
      for (int mt = 0; mt < 4; ++mt)
        for (int nt = 0; nt < 4; ++nt)
          acc[mt][nt] = __builtin_amdgcn_mfma_f32_16x16x32_bf16(af[mt], bfv[nt], acc[mt][nt], 0, 0, 0);
    }
    __syncthreads();
  }

  // epilogue
  for (int mt = 0; mt < 4; ++mt) {
    for (int nt = 0; nt < 4; ++nt) {
      const int coll = wn * 64 + nt * 16 + (lane & 15);
      const int colg = n0 + coll;
      const float bv = bias[colg];
      const float extra = (MODE == 0) ? sval * aux[colg] : 0.f;
      for (int r = 0; r < 4; ++r) {
        const int rowl = wm * 64 + mt * 16 + ((lane >> 4) << 2) + r;
        const size_t rowg = m0 + rowl;
        const float g = acc[mt][nt][r] + bv + extra;
        if (MODE == 0) {
          Abf_out[rowg * 512 + colg] = f2bf(fast_tanh(g));
        } else {
          const float tt = aux[rowg];
          Yd[rowg * 512 + colg] = fmaf(sval * tt, g, Yd[rowg * 512 + colg]);
        }
      }
    }
  }
}

// ---------------------------------------------------------------------------
extern "C" void kernel_launch(void* const* d_in, const int* in_sizes, int n_in,
                              void* d_out, int out_size, void* d_ws, size_t ws_size,
                              hipStream_t stream) {
  const float* x    = (const float*)d_in[0];
  const float* t    = (const float*)d_in[1];
  const float* W_ih = (const float*)d_in[2];
  const float* W_hh = (const float*)d_in[3];
  const float* b_ih = (const float*)d_in[4];
  const float* b_hh = (const float*)d_in[5];
  const float* w1   = (const float*)d_in[6];
  const float* b1   = (const float*)d_in[7];
  const float* w2   = (const float*)d_in[8];
  const float* b2   = (const float*)d_in[9];
  float* Yd = (float*)d_out;   // (B,T,H) fp32; doubles as ODE state Y

  char* ws = (char*)d_ws;
  size_t off = 0;
  auto alloc = [&](size_t bytes) {
    void* p = ws + off;
    off += (bytes + 255) & ~(size_t)255;
    return p;
  };
  u16*   Whh_bf = (u16*)alloc((size_t)G4_ * H_ * 2);   //   2 MB
  u16*   Wih_bf = (u16*)alloc((size_t)G4_ * D_ * 2);   // 512 KB
  u16*   w1y_bf = (u16*)alloc((size_t)H_ * H_ * 2);    // 512 KB
  u16*   w2_bf  = (u16*)alloc((size_t)H_ * H_ * 2);    // 512 KB
  float* w1s    = (float*)alloc(H_ * 4);
  float* bsum   = (float*)alloc(G4_ * 4);
  float* cst    = (float*)alloc((size_t)B_ * H_ * 4);  // 512 KB
  u16*   Abf    = (u16*)alloc((size_t)BT_ * H_ * 2);   // 256 MB

  prep_kernel<<<4096, 256, 0, stream>>>(W_hh, W_ih, w1, w2, b_ih, b_hh,
                                        Whh_bf, Wih_bf, w1y_bf, w2_bf, w1s, bsum, cst, Yd);

  // Phase 1: sequential LSTM; h_{i+1} written for i = 0..T-2 (out[:,0,:] = 0 from prep)
  for (int step = 0; step < T_ - 1; ++step)
    lstm_step_kernel<<<dim3(16, 8), 256, 0, stream>>>(x, Whh_bf, Wih_bf, bsum, cst, Yd, step);

  // Phase 2: 4 Euler steps, each = two fused GEMMs over all B*T rows
  for (int k = 0; k < 4; ++k) {
    ode_gemm<0><<<dim3(4, 2048), 256, 0, stream>>>(Yd, w1y_bf, b1, w1s, nullptr, Abf, 0.25f * k);
    ode_gemm<1><<<dim3(4, 2048), 256, 0, stream>>>(Abf, w2_bf, b2, t, Yd, nullptr, 0.25f);
  }
}